// Round 3
// baseline (421.057 us; speedup 1.0000x reference)
//
#include <hip/hip_runtime.h>

#define N_NODES 20000
#define NPAIRS  10000
#define N_EDGES 320000
#define CAP     64
#define KN      15
#define GRID_MAIN 2500

typedef _Float16 half_t;
typedef _Float16 half2_t __attribute__((ext_vector_type(2)));
typedef _Float16 half8_t __attribute__((ext_vector_type(8)));

// params float-index layout
#define P_ALPHA 0
#define P_BETA  1
#define P_IEPS2 2
#define P_EPS   3
#define P_HC2   16
#define P_RSC2  216
#define P_F1    316

// workspace byte offsets
#define OFF_CNT    0u             // 80 KB
#define OFF_S2X    80000u         // 80 KB
#define OFF_STATS  160000u        // 65 doubles (520 B)
#define OFF_FLAG   160520u        // last-block-done counter
#define OFF_NBC    160528u
#define OFF_NEIGH  240528u
#define OFF_BUF    1440528u       // 5.12 MB; reused as xh (2.56 MB) after selstats
#define OFF_PARAMS 6560528u
#define MEMSET_LEN 160528u        // cnt + s2x(harmless) + stats + flag

// tf_l per-template stride (halfs): dword stride 324 = 4 (mod 32)
#define TF_STRIDE 648

// ---- 16-lane reduction via DPP row_ror adds: pure VALU ----
template<int CTRL>
__device__ __forceinline__ float dpp_add(float v) {
  int s = __builtin_bit_cast(int, v);
  int r = __builtin_amdgcn_update_dpp(0, s, CTRL, 0xF, 0xF, true);
  return v + __builtin_bit_cast(float, r);
}
__device__ __forceinline__ float sum16(float v) {
  v = dpp_add<0x128>(v);   // row_ror:8
  v = dpp_add<0x124>(v);   // row_ror:4
  v = dpp_add<0x122>(v);   // row_ror:2
  v = dpp_add<0x121>(v);   // row_ror:1
  return v;
}
// ds_swizzle imm BitMode 0x010: new_lane = lane&0x10 -> broadcast k=0 of group
__device__ __forceinline__ float bcast16(float v) {
  return __builtin_bit_cast(float,
      __builtin_amdgcn_ds_swizzle(__builtin_bit_cast(int, v), 0x010));
}
__device__ __forceinline__ float fdot2(half2_t a, half2_t b, float c) {
  return __builtin_amdgcn_fdot2(a, b, c, false);
}
__device__ __forceinline__ half2_t h2(unsigned int u) {
  return __builtin_bit_cast(half2_t, u);
}
// force a wave-uniform float into an SGPR
__device__ __forceinline__ float sgpr(float v) {
  return __builtin_bit_cast(float,
      __builtin_amdgcn_readfirstlane(__builtin_bit_cast(int, v)));
}

// ---------------- kernel 1: scatter edge ids per source node ----------------
__global__ void k_scatter(const int* __restrict__ ei, int* __restrict__ cnt,
                          int* __restrict__ buf) {
  int e = blockIdx.x * blockDim.x + threadIdx.x;
  if (e >= N_EDGES) return;
  int s = ei[e];
  int slot = atomicAdd(&cnt[s], 1);
  if (slot < CAP) buf[s * CAP + slot] = e;
}

// ---- kernel 2: select 15 smallest edge ids + fused eps-stats + finalize ----
#define SS_BLOCKS 1250
__global__ void __launch_bounds__(256)
k_selstats(const int* __restrict__ ei, const int* __restrict__ cnt,
           const int* __restrict__ buf, const float* __restrict__ x,
           int* __restrict__ nbc_g, int* __restrict__ neigh,
           float* __restrict__ s2xh, double* __restrict__ stats,
           int* __restrict__ flag,
           const float* __restrict__ tf, const float* __restrict__ c2,
           const float* __restrict__ alpha0, float* __restrict__ params) {
  const int lane = threadIdx.x & 63;
  const int wid = threadIdx.x >> 6;
  const int* dst = ei + N_EDGES;
  const float x0 = x[lane];          // x[0,f] (lane = feature)
  const float x0sq = x0 * x0;
  float accx = 0.f, acc2 = 0.f;      // per-lane(feature) weighted sums
  __shared__ int dsh[4][16];         // per-wave staging of selected neighbors

  for (int w = blockIdx.x * 4 + wid; w < N_NODES; w += SS_BLOCKS * 4) {
    int c = cnt[w];
    int cc = c < CAP ? c : CAP;
    int e = (lane < cc) ? buf[w * CAP + lane] : 0x7fffffff;
    int nb = c < KN ? c : KN;
    bool sel;
    if (cc <= KN) {
      sel = lane < cc;
    } else {
      int rank = 0;
      for (int j = 0; j < cc; j++) {      // cc is wave-uniform
        int ej = __shfl(e, j);
        rank += (ej < e) ? 1 : 0;
      }
      sel = (e != 0x7fffffff) && (rank < KN);  // distinct ids -> exactly 15
    }
    unsigned long long mask = __ballot(sel);
    int d = sel ? dst[e] : 0;
    if (sel) {
      int pos = __popcll(mask & ((1ull << lane) - 1ull));
      neigh[w * KN + pos] = d;
      dsh[wid][pos] = d;               // intra-wave LDS staging
    }
    if (lane == 0) nbc_g[w] = nb;

    // ---- stats: lane = feature ----
    float sv = x[w * 64 + lane];
    {   // s2xh[w] = sum_f (f16(x))^2  (RTNE cast, matches k_main conversion)
      float hv = (float)(half_t)sv;
      float sq = hv * hv;
#pragma unroll
      for (int off = 32; off > 0; off >>= 1) sq += __shfl_xor(sq, off, 64);
      if (lane == 0) s2xh[w] = sq;
    }
    float ax = sv, a2 = sv * sv;
    // read all (up to 15) neighbor indices, then issue loads independently
    int idx[KN];
#pragma unroll
    for (int r = 0; r < KN; r++) idx[r] = dsh[wid][r];   // garbage beyond nb: unused
#pragma unroll
    for (int r = 0; r < KN; r++) {
      if (r < nb) {                        // nb is wave-uniform -> uniform branch
        float nv = x[(size_t)idx[r] * 64 + lane];
        ax += nv;
        a2 = fmaf(nv, nv, a2);
      }
    }
    float w0 = (float)(KN - nb);
    ax = fmaf(w0, x0, ax);
    a2 = fmaf(w0, x0sq, a2);
    accx += ax;
    acc2 += a2;
  }

  // ---- block reduction + global atomics ----
#pragma unroll
  for (int off = 32; off > 0; off >>= 1) acc2 += __shfl_xor(acc2, off, 64);
  __shared__ float redx[4][64];
  __shared__ float red2[4];
  __shared__ int lastsh;
  redx[wid][lane] = accx;
  if (lane == 0) red2[wid] = acc2;
  __syncthreads();
  int tid = threadIdx.x;
  if (tid < 64) {
    float s = redx[0][tid] + redx[1][tid] + redx[2][tid] + redx[3][tid];
    atomicAdd(&stats[1 + tid], (double)s);
  }
  if (tid == 0)
    atomicAdd(&stats[0], (double)(red2[0] + red2[1] + red2[2] + red2[3]));
  __syncthreads();
  if (tid == 0) {
    __threadfence();
    int old = atomicAdd(flag, 1);
    lastsh = (old == SS_BLOCKS - 1) ? 1 : 0;
  }
  __syncthreads();
  if (!lastsh) return;
  __threadfence();   // acquire: all blocks' stats atomics visible
  // ------- finalize (runs once, in the last-finishing block) -------
  __shared__ float sh[4];
  if (tid < 64) {
    float s = 0.f, s2 = 0.f;
    for (int tm = 0; tm < 100; tm++) { float v = tf[tm * 64 + tid]; s += v; s2 += v * v; }
    double inv16N = 1.0 / (double)(N_NODES * 16);
    double cross = (stats[1 + tid] * inv16N) * ((double)s / 100.0);
    double B = (double)s2 / 100.0;
    double term = B - 2.0 * cross;
#pragma unroll
    for (int off = 32; off > 0; off >>= 1) term += __shfl_xor(term, off, 64);
    if (tid == 0) {
      double A = stats[0] * inv16N;
      double meanM = A + term;
      float eps = (float)(0.05 * meanM) + 1e-6f;
      float a0 = alpha0[0];
      float alpha = 1.f / (1.f + expf(-a0));
      params[P_ALPHA] = alpha;
      params[P_BETA]  = 1.f - alpha;
      params[P_IEPS2] = 1.4426950408889634f / eps;
      params[P_EPS]   = eps;
      sh[0] = alpha; sh[1] = 1.f - alpha; sh[2] = 1.4426950408889634f / eps;
    }
  }
  __syncthreads();
  if (tid < 100) {
    float alpha = sh[0], beta = sh[1], ieps2 = sh[2];
    int t = tid / 10, mm = tid % 10;
    float h = 0.f;
    for (int r = 0; r < 10; r++) { float cv = c2[t * 100 + mm * 10 + r]; h += cv * cv; }
    float hc2v = 0.1f * h;
    params[P_HC2 + tid] = hc2v;
    float s2 = 0.f;
    for (int f = 0; f < 64; f++) { float v = tf[tid * 64 + f]; s2 += v * v; }
    float rs = 0.f;
    for (int m2_ = 0; m2_ < 10; m2_++) rs += c2[t * 100 + mm * 10 + m2_];
    params[P_RSC2 + tid] = rs;
    params[P_F1 + tid] = (beta * s2 + 2.0f * alpha * hc2v) * (-ieps2);
  }
}

// ------- kernel 2.5: x (f32) -> xh (f16, RTNE), written into dead buf ------
__global__ void __launch_bounds__(256)
k_xhalf(const float* __restrict__ x, half_t* __restrict__ xh) {
  int i = (blockIdx.x * 256 + threadIdx.x) * 8;
  float4 a = *(const float4*)(x + i);
  float4 b = *(const float4*)(x + i + 4);
  half8_t h = { (half_t)a.x, (half_t)a.y, (half_t)a.z, (half_t)a.w,
                (half_t)b.x, (half_t)b.y, (half_t)b.z, (half_t)b.w };
  *(half8_t*)(xh + i) = h;
}

// --------- kernel 3: TWO-pair interleaved fused M + Sinkhorn ----------------
// lane = (node_s, t, k). Each block iterates 2x over TWO independent pairs
// (p, p+2500) interleaved in-register: doubles per-wave ILP in the
// latency-chained Sinkhorn phases (sum16 DPP chains, rcp/exp2 trans ops) and
// amortizes the tf_l LDS reads across 2 pairs. All doubled state is touched
// every inner iteration -> register-allocated, not scratch.
__global__ void __launch_bounds__(320, 3)
k_main(const half_t* __restrict__ xh, const float* __restrict__ tf_g,
       const float* __restrict__ c2_g, const int* __restrict__ nbc_g,
       const int* __restrict__ neigh_g, const float* __restrict__ params,
       const float* __restrict__ s2x_g, float* __restrict__ out) {
  __shared__ __align__(16) half_t tf_l[10 * TF_STRIDE];   // 12.96 KB
  __shared__ __align__(16) float c2_l[1000];              // 4 KB
  __shared__ __align__(16) float hc2_l[100];
  __shared__ __align__(16) float rsc2_l[100];
  __shared__ __align__(16) float F1_l[100];
  __shared__ __align__(16) float bsb_l[2][20][10][2];     // [pair][grp][kc][B/SB]

  const int tid = threadIdx.x;
  const int node_s = tid / 160;
  const int s = tid % 160;
  const int t = s >> 4;
  const int k = s & 15;
  const bool k0 = (k == 0);
  const int grp = node_s * 10 + t;

  for (int i = tid; i < 6400; i += 320) {
    int tt = i / 640, rem = i - tt * 640;
    tf_l[tt * TF_STRIDE + rem] = (half_t)tf_g[i];
  }
  for (int i = tid; i < 1000; i += 320) c2_l[i] = c2_g[i];
  if (tid < 100) {
    hc2_l[tid]  = params[P_HC2 + tid];
    rsc2_l[tid] = params[P_RSC2 + tid];
    F1_l[tid]   = params[P_F1 + tid];
  }

  // wave-uniform constants -> SGPRs
  const float alpha = sgpr(params[P_ALPHA]);
  const float beta  = sgpr(params[P_BETA]);
  const float ieps2 = sgpr(params[P_IEPS2]);
  const float eps   = sgpr(params[P_EPS]);
  const float niep  = -ieps2;
  const float twoal = 2.0f * alpha;
  const float ctv10 = 0.2f * twoal * ieps2;    // = ctv*0.1 (drift-compensated)
  const float cab   = 2.0f * beta * ieps2;
  const float c_a2d = -eps * 0.69314718056f;   // Ab -> (beta*M + 2a*cc)
  const float twoal01 = 0.1f * twoal;

  const int idx_c2 = t * 100 + ((k < 10) ? k : 9) * 10;   // C2[t][kc][*] base
  __syncthreads();

  const int kk = (k == 0) ? 0 : (k - 1);
  const half_t* tfb = &tf_l[t * TF_STRIDE];

  // prefetch pointer-chase chains for iteration 0 (pairs bid, bid+2500)
  int nbA_pf  = nbc_g[2 * blockIdx.x + node_s];
  int nbrA_pf = neigh_g[(2 * blockIdx.x + node_s) * KN + kk];
  int nbB_pf  = nbc_g[2 * (blockIdx.x + 2500) + node_s];
  int nbrB_pf = neigh_g[(2 * (blockIdx.x + 2500) + node_s) * KN + kk];

#pragma unroll 1
  for (int ii = 0; ii < 2; ii++) {
    const int pA = blockIdx.x + ii * 5000;
    const int pB = pA + 2500;
    const int vA = 2 * pA + node_s;
    const int vB = 2 * pB + node_s;
    const int nbA = nbA_pf, nbB = nbB_pf;
    const int srcA = k0 ? vA : (kk < nbA ? nbrA_pf : 0);
    const int srcB = k0 ? vB : (kk < nbB ? nbrB_pf : 0);
    const float s2xA = s2x_g[srcA];
    const float s2xB = s2x_g[srcB];
    const uint4* xrA = (const uint4*)(xh + (size_t)srcA * 64);
    const uint4* xrB = (const uint4*)(xh + (size_t)srcB * 64);

    // ---- issue both 128B rows: 16 independent uint4 loads ----
    uint4 qA[8], qB[8];
#pragma unroll
    for (int r = 0; r < 8; r++) { qA[r] = xrA[r]; qB[r] = xrB[r]; }

    // prefetch next iteration's chains (clamped; unused when ii==1)
    {
      int vAn = 2 * (pA + 5000) + node_s; vAn = vAn < N_NODES ? vAn : 0;
      int vBn = 2 * (pB + 5000) + node_s; vBn = vBn < N_NODES ? vBn : 0;
      nbA_pf = nbc_g[vAn];  nbrA_pf = neigh_g[vAn * KN + kk];
      nbB_pf = nbc_g[vBn];  nbrB_pf = neigh_g[vBn * KN + kk];
    }

    // ---- M dot products, both pairs share the tf_l reads ----
    float accA[10], accB[10];
#pragma unroll
    for (int m = 0; m < 10; m++) {
      float a = 0.0f, b = 0.0f;
#pragma unroll
      for (int ch = 0; ch < 4; ch++) {
        uint4 tqa = *(const uint4*)&tfb[m * 64 + ch * 16];
        uint4 tqb = *(const uint4*)&tfb[m * 64 + ch * 16 + 8];
        const uint4 qa = qA[2 * ch];
        const uint4 qb = qA[2 * ch + 1];
        const uint4 ra = qB[2 * ch];
        const uint4 rb = qB[2 * ch + 1];
        a = fdot2(h2(tqa.x), h2(qa.x), a);
        b = fdot2(h2(tqa.x), h2(ra.x), b);
        a = fdot2(h2(tqa.y), h2(qa.y), a);
        b = fdot2(h2(tqa.y), h2(ra.y), b);
        a = fdot2(h2(tqa.z), h2(qa.z), a);
        b = fdot2(h2(tqa.z), h2(ra.z), b);
        a = fdot2(h2(tqa.w), h2(qa.w), a);
        b = fdot2(h2(tqa.w), h2(ra.w), b);
        a = fdot2(h2(tqb.x), h2(qb.x), a);
        b = fdot2(h2(tqb.x), h2(rb.x), b);
        a = fdot2(h2(tqb.y), h2(qb.y), a);
        b = fdot2(h2(tqb.y), h2(rb.y), b);
        a = fdot2(h2(tqb.z), h2(qb.z), a);
        b = fdot2(h2(tqb.z), h2(rb.z), b);
        a = fdot2(h2(tqb.w), h2(qb.w), a);
        b = fdot2(h2(tqb.w), h2(rb.w), b);
      }
      accA[m] = a;
      accB[m] = b;
    }

    // ---- per-pair scalars ----
    const float invA = 1.0f / (float)(1 + nbA);
    const float invB = 1.0f / (float)(1 + nbB);
    const float pkA = (k <= nbA) ? invA : 0.0f;
    const float pkB = (k <= nbB) ? invB : 0.0f;
    const float hC1kA = (k == 0) ? (float)nbA * invA : ((k <= nbA) ? invA : 0.0f);
    const float hC1kB = (k == 0) ? (float)nbB * invB : ((k <= nbB) ? invB : 0.0f);
    const float baseA = (beta * s2xA + twoal * hC1kA) * niep;
    const float baseB = (beta * s2xB + twoal * hC1kB) * niep;
    const float ctmA  = ctv10 * ((k == 0) ? (float)nbA * invA : invA);
    const float ctmB  = ctv10 * ((k == 0) ? (float)nbB * invB : invB);

    float AbA[10], AbB[10];
#pragma unroll
    for (int j = 0; j < 5; j++) {
      float2 f1v = *(const float2*)&F1_l[t * 10 + 2 * j];
      AbA[2 * j]     = fmaf(cab, accA[2 * j],     f1v.x + baseA);
      AbB[2 * j]     = fmaf(cab, accB[2 * j],     f1v.x + baseB);
      AbA[2 * j + 1] = fmaf(cab, accA[2 * j + 1], f1v.y + baseA);
      AbB[2 * j + 1] = fmaf(cab, accB[2 * j + 1], f1v.y + baseB);
    }

    float KA[10], KB[10], vvA[10], vvB[10];
    float uA = 1.0f, uB = 1.0f;
#pragma unroll
    for (int m = 0; m < 10; m++) { vvA[m] = 1.0f; vvB[m] = 1.0f; }

    // ---- outer 0: Tp = p (x) q -> tv from rowsum(C2) ----
#pragma unroll
    for (int j = 0; j < 5; j++) {
      float2 rs = *(const float2*)&rsc2_l[t * 10 + 2 * j];
      KA[2 * j]     = __builtin_amdgcn_exp2f(fmaf(ctmA, rs.x, AbA[2 * j]));
      KB[2 * j]     = __builtin_amdgcn_exp2f(fmaf(ctmB, rs.x, AbB[2 * j]));
      KA[2 * j + 1] = __builtin_amdgcn_exp2f(fmaf(ctmA, rs.y, AbA[2 * j + 1]));
      KB[2 * j + 1] = __builtin_amdgcn_exp2f(fmaf(ctmB, rs.y, AbB[2 * j + 1]));
    }

#pragma unroll 1
    for (int o = 0; o < 3; o++) {
      // 5 drift-folded Sinkhorn iterations, A/B interleaved
#pragma unroll 1
      for (int it = 0; it < 5; it++) {
        float kvA0 = 0.0f, kvA1 = 0.0f, kvB0 = 0.0f, kvB1 = 0.0f;
#pragma unroll
        for (int m = 0; m < 10; m += 2) {
          kvA0 = fmaf(KA[m],     vvA[m],     kvA0);
          kvB0 = fmaf(KB[m],     vvB[m],     kvB0);
          kvA1 = fmaf(KA[m + 1], vvA[m + 1], kvA1);
          kvB1 = fmaf(KB[m + 1], vvB[m + 1], kvB1);
        }
        uA = pkA * __builtin_amdgcn_rcpf(kvA0 + kvA1);
        uB = pkB * __builtin_amdgcn_rcpf(kvB0 + kvB1);
#pragma unroll
        for (int m = 0; m < 10; m++) {
          float wA = sum16(KA[m] * uA);
          float wB = sum16(KB[m] * uB);
          vvA[m] = __builtin_amdgcn_rcpf(wA);
          vvB[m] = __builtin_amdgcn_rcpf(wB);
        }
      }
      if (o == 2) break;
      // ---- site: recompute K from current Tp (tk' = 10*Tp), both pairs ----
      {
        float BA = 0.0f, SBA = 0.0f, BB = 0.0f, SBB = 0.0f;
#pragma unroll
        for (int j = 0; j < 5; j++) {
          float2 c2p = *(const float2*)&c2_l[idx_c2 + 2 * j];
          float tkaA = KA[2 * j] * vvA[2 * j] * uA;
          float tkaB = KB[2 * j] * vvB[2 * j] * uB;
          float tkbA = KA[2 * j + 1] * vvA[2 * j + 1] * uA;
          float tkbB = KB[2 * j + 1] * vvB[2 * j + 1] * uB;
          BA  = fmaf(bcast16(tkaA), c2p.x, BA);
          BB  = fmaf(bcast16(tkaB), c2p.x, BB);
          SBA = fmaf(sum16(tkaA),   c2p.x, SBA);
          SBB = fmaf(sum16(tkaB),   c2p.x, SBB);
          BA  = fmaf(bcast16(tkbA), c2p.y, BA);
          BB  = fmaf(bcast16(tkbB), c2p.y, BB);
          SBA = fmaf(sum16(tkbA),   c2p.y, SBA);
          SBB = fmaf(sum16(tkbB),   c2p.y, SBB);
        }
        if (k < 10) {
          bsb_l[0][grp][k][0] = BA; bsb_l[0][grp][k][1] = SBA;
          bsb_l[1][grp][k][0] = BB; bsb_l[1][grp][k][1] = SBB;
        }
        __threadfence_block();
#pragma unroll
        for (int j = 0; j < 5; j++) {
          float4 bvA = *(const float4*)&bsb_l[0][grp][2 * j][0];
          float4 bvB = *(const float4*)&bsb_l[1][grp][2 * j][0];
          float tvaA = k0 ? (bvA.y - bvA.x) : bvA.x;
          float tvaB = k0 ? (bvB.y - bvB.x) : bvB.x;
          float tvbA = k0 ? (bvA.w - bvA.z) : bvA.z;
          float tvbB = k0 ? (bvB.w - bvB.z) : bvB.z;
          KA[2 * j]     = __builtin_amdgcn_exp2f(fmaf(ctv10, tvaA, AbA[2 * j]));
          KB[2 * j]     = __builtin_amdgcn_exp2f(fmaf(ctv10, tvaB, AbB[2 * j]));
          KA[2 * j + 1] = __builtin_amdgcn_exp2f(fmaf(ctv10, tvbA, AbA[2 * j + 1]));
          KB[2 * j + 1] = __builtin_amdgcn_exp2f(fmaf(ctv10, tvbB, AbB[2 * j + 1]));
        }
        __threadfence_block();
      }
    }

    // ---- final: distance for both pairs ----
    {
      float tkA[10], tkB[10];
      float BA = 0.0f, SBA = 0.0f, BB = 0.0f, SBB = 0.0f;
#pragma unroll
      for (int j = 0; j < 5; j++) {
        float2 c2p = *(const float2*)&c2_l[idx_c2 + 2 * j];
        tkA[2 * j]     = KA[2 * j] * vvA[2 * j] * uA;
        tkB[2 * j]     = KB[2 * j] * vvB[2 * j] * uB;
        tkA[2 * j + 1] = KA[2 * j + 1] * vvA[2 * j + 1] * uA;
        tkB[2 * j + 1] = KB[2 * j + 1] * vvB[2 * j + 1] * uB;
        BA  = fmaf(bcast16(tkA[2 * j]), c2p.x, BA);
        BB  = fmaf(bcast16(tkB[2 * j]), c2p.x, BB);
        SBA = fmaf(sum16(tkA[2 * j]),   c2p.x, SBA);
        SBB = fmaf(sum16(tkB[2 * j]),   c2p.x, SBB);
        BA  = fmaf(bcast16(tkA[2 * j + 1]), c2p.y, BA);
        BB  = fmaf(bcast16(tkB[2 * j + 1]), c2p.y, BB);
        SBA = fmaf(sum16(tkA[2 * j + 1]),   c2p.y, SBA);
        SBB = fmaf(sum16(tkB[2 * j + 1]),   c2p.y, SBB);
      }
      if (k < 10) {
        bsb_l[0][grp][k][0] = BA; bsb_l[0][grp][k][1] = SBA;
        bsb_l[1][grp][k][0] = BB; bsb_l[1][grp][k][1] = SBB;
      }
      __threadfence_block();
      float ddA = 0.0f, ddB = 0.0f;
#pragma unroll
      for (int j = 0; j < 5; j++) {
        float4 bvA = *(const float4*)&bsb_l[0][grp][2 * j][0];
        float4 bvB = *(const float4*)&bsb_l[1][grp][2 * j][0];
        float2 h2v = *(const float2*)&hc2_l[t * 10 + 2 * j];
        float tvaA = k0 ? (bvA.y - bvA.x) : bvA.x;
        float tvaB = k0 ? (bvB.y - bvB.x) : bvB.x;
        float tvbA = k0 ? (bvA.w - bvA.z) : bvA.z;
        float tvbB = k0 ? (bvB.w - bvB.z) : bvB.z;
        float c1aA = fmaf(alpha, hC1kA + h2v.x, twoal01 * tvaA);
        float c1aB = fmaf(alpha, hC1kB + h2v.x, twoal01 * tvaB);
        float c1bA = fmaf(alpha, hC1kA + h2v.y, twoal01 * tvbA);
        float c1bB = fmaf(alpha, hC1kB + h2v.y, twoal01 * tvbB);
        float coaA = fmaf(c_a2d, AbA[2 * j], -c1aA);
        float coaB = fmaf(c_a2d, AbB[2 * j], -c1aB);
        float cobA = fmaf(c_a2d, AbA[2 * j + 1], -c1bA);
        float cobB = fmaf(c_a2d, AbB[2 * j + 1], -c1bB);
        ddA = fmaf(coaA, tkA[2 * j], ddA);
        ddB = fmaf(coaB, tkB[2 * j], ddB);
        ddA = fmaf(cobA, tkA[2 * j + 1], ddA);
        ddB = fmaf(cobB, tkB[2 * j + 1], ddB);
      }
      __threadfence_block();
      ddA = sum16(ddA * 0.1f);
      ddB = sum16(ddB * 0.1f);
      if (k == 0) {
        out[vA * 10 + t] = ddA;
        out[vB * 10 + t] = ddB;
      }
    }
  }
}

extern "C" void kernel_launch(void* const* d_in, const int* in_sizes, int n_in,
                              void* d_out, int out_size, void* d_ws, size_t ws_size,
                              hipStream_t stream) {
  const float* x  = (const float*)d_in[0];
  const int*   ei = (const int*)d_in[1];
  const float* c2 = (const float*)d_in[2];
  const float* tf = (const float*)d_in[3];
  const float* a0 = (const float*)d_in[4];
  float* out = (float*)d_out;
  char* ws = (char*)d_ws;
  int*    cnt    = (int*)(ws + OFF_CNT);
  float*  s2xh   = (float*)(ws + OFF_S2X);
  double* stats  = (double*)(ws + OFF_STATS);
  int*    flag   = (int*)(ws + OFF_FLAG);
  int*    nbc    = (int*)(ws + OFF_NBC);
  int*    neigh  = (int*)(ws + OFF_NEIGH);
  int*    buf    = (int*)(ws + OFF_BUF);
  half_t* xhalf  = (half_t*)(ws + OFF_BUF);   // reuses buf after selstats
  float*  params = (float*)(ws + OFF_PARAMS);
  (void)in_sizes; (void)n_in; (void)out_size; (void)ws_size;

  hipMemsetAsync(ws, 0, MEMSET_LEN, stream);   // zero cnt, stats, flag
  k_scatter<<<N_EDGES / 256, 256, 0, stream>>>(ei, cnt, buf);
  k_selstats<<<SS_BLOCKS, 256, 0, stream>>>(ei, cnt, buf, x, nbc, neigh,
                                            s2xh, stats, flag, tf, c2, a0, params);
  k_xhalf<<<625, 256, 0, stream>>>(x, xhalf);   // buf is dead from here on
  k_main<<<GRID_MAIN, 320, 0, stream>>>(xhalf, tf, c2, nbc, neigh, params, s2xh, out);
}

// Round 4
// 381.875 us; speedup vs baseline: 1.1026x; 1.1026x over previous
//
#include <hip/hip_runtime.h>

#define N_NODES 20000
#define NPAIRS  10000
#define N_EDGES 320000
#define CAP     48
#define KN      15
#define GRID_MAIN 2500

typedef _Float16 half_t;
typedef _Float16 half2_t __attribute__((ext_vector_type(2)));

// params float-index layout
#define P_ALPHA 0
#define P_BETA  1
#define P_IEPS2 2
#define P_EPS   3
#define P_HC2   16
#define P_RSC2  216
#define P_F1    316

// workspace byte offsets
#define OFF_CNT    0u             // 80 KB
#define OFF_S2X    80000u         // 80 KB
#define OFF_STATS  160000u        // 65 doubles (520 B)
#define OFF_FLAG   160520u        // last-block-done counter (int)
#define OFF_PAD    160524u        // global pad count (int)
#define OFF_NBC    160528u
#define OFF_NEIGH  240528u
#define OFF_BUF    1440528u       // 3.84 MB edge-slot buf; xh (2.56 MB) overwrites
#define OFF_WCT    5280528u       // 80 KB neighbor-weight counters (in old buf tail)
#define OFF_PARAMS 6560528u
#define MEMSET_LEN 160528u        // cnt + s2x(harmless) + stats + flag + pad

// tf_l per-template stride (halfs): dword stride 324 = 4 (mod 32)
#define TF_STRIDE 648

// ---- 16-lane reduction via DPP row_ror adds: pure VALU ----
template<int CTRL>
__device__ __forceinline__ float dpp_add(float v) {
  int s = __builtin_bit_cast(int, v);
  int r = __builtin_amdgcn_update_dpp(0, s, CTRL, 0xF, 0xF, true);
  return v + __builtin_bit_cast(float, r);
}
__device__ __forceinline__ float sum16(float v) {
  v = dpp_add<0x128>(v);   // row_ror:8
  v = dpp_add<0x124>(v);   // row_ror:4
  v = dpp_add<0x122>(v);   // row_ror:2
  v = dpp_add<0x121>(v);   // row_ror:1
  return v;
}
// ds_swizzle imm BitMode 0x010: new_lane = lane&0x10 -> broadcast k=0 of group
__device__ __forceinline__ float bcast16(float v) {
  return __builtin_bit_cast(float,
      __builtin_amdgcn_ds_swizzle(__builtin_bit_cast(int, v), 0x010));
}
__device__ __forceinline__ float fdot2(half2_t a, half2_t b, float c) {
  return __builtin_amdgcn_fdot2(a, b, c, false);
}
__device__ __forceinline__ half2_t h2(unsigned int u) {
  return __builtin_bit_cast(half2_t, u);
}
// force a wave-uniform float into an SGPR
__device__ __forceinline__ float sgpr(float v) {
  return __builtin_bit_cast(float,
      __builtin_amdgcn_readfirstlane(__builtin_bit_cast(int, v)));
}

// ---------------- kernel 1: scatter edge ids per source node ----------------
__global__ void k_scatter(const int* __restrict__ ei, int* __restrict__ cnt,
                          int* __restrict__ buf) {
  int e = blockIdx.x * blockDim.x + threadIdx.x;
  if (e >= N_EDGES) return;
  int s = ei[e];
  int slot = atomicAdd(&cnt[s], 1);
  if (slot < CAP) buf[s * CAP + slot] = e;
}

// ---- kernel 2: select 15 smallest edge ids, scatter neighbor weights ------
// No x reads here: stats are computed as a weighted single pass in k_pass.
#define SS_BLOCKS 1250
__global__ void __launch_bounds__(256)
k_sel(const int* __restrict__ ei, const int* __restrict__ cnt,
      const int* __restrict__ buf, int* __restrict__ nbc_g,
      int* __restrict__ neigh, int* __restrict__ wct,
      int* __restrict__ padc) {
  const int lane = threadIdx.x & 63;
  const int wid = threadIdx.x >> 6;
  const int* dst = ei + N_EDGES;
  __shared__ int padsh;
  if (threadIdx.x == 0) padsh = 0;
  __syncthreads();
  int padacc = 0;

  for (int w = blockIdx.x * 4 + wid; w < N_NODES; w += SS_BLOCKS * 4) {
    int c = cnt[w];
    int cc = c < CAP ? c : CAP;
    int e = (lane < cc) ? buf[w * CAP + lane] : 0x7fffffff;
    int nb = c < KN ? c : KN;
    bool sel;
    if (cc <= KN) {
      sel = lane < cc;
    } else {
      int rank = 0;
      for (int j = 0; j < cc; j++) {      // cc is wave-uniform
        int ej = __shfl(e, j);
        rank += (ej < e) ? 1 : 0;
      }
      sel = (e != 0x7fffffff) && (rank < KN);  // distinct ids -> exactly 15
    }
    unsigned long long mask = __ballot(sel);
    if (sel) {
      int pos = __popcll(mask & ((1ull << lane) - 1ull));
      int d = dst[e];
      neigh[w * KN + pos] = d;
      atomicAdd(&wct[d], 1);             // neighbor-occurrence weight
    }
    if (lane == 0) { nbc_g[w] = nb; padacc += KN - nb; }
  }
  if (lane == 0 && padacc) atomicAdd(&padsh, padacc);
  __syncthreads();
  if (threadIdx.x == 0 && padsh) atomicAdd(padc, padsh);
}

// ---- kernel 2.5: ONE coalesced pass over x ---------------------------------
// Produces xh (f16 RTNE), s2xh (row sum of f16(x)^2), weighted eps-stats
// (sum_n w[n]*x[n,f], sum_n w[n]*|x[n]|^2), then last block finalizes params.
// w[n] = 1(self) + wct[n](neighbor occurrences) + (n==0)*pad (short rows pad
// with node 0, matching the original srcn=0 fallback).
#define PB 200
__global__ void __launch_bounds__(256)
k_pass(const float* __restrict__ x, half_t* __restrict__ xh,
       const int* __restrict__ wct, const int* __restrict__ padc,
       float* __restrict__ s2xh, double* __restrict__ stats,
       int* __restrict__ flag, const float* __restrict__ tf,
       const float* __restrict__ c2, const float* __restrict__ alpha0,
       float* __restrict__ params) {
  const int lane = threadIdx.x & 63;
  const int wid = threadIdx.x >> 6;
  const int tid = threadIdx.x;
  const int pad = *padc;
  float accx = 0.f, acc2 = 0.f;

  for (int n = blockIdx.x * 4 + wid; n < N_NODES; n += PB * 4) {
    float xv = x[n * 64 + lane];
    half_t hv = (half_t)xv;              // RTNE, matches k_main path
    xh[n * 64 + lane] = hv;
    float hf = (float)hv;
    float sq = hf * hf;
#pragma unroll
    for (int off = 32; off > 0; off >>= 1) sq += __shfl_xor(sq, off, 64);
    if (lane == 0) s2xh[n] = sq;
    float wt = (float)(1 + wct[n] + ((n == 0) ? pad : 0));
    accx = fmaf(wt, xv, accx);
    acc2 = fmaf(wt, xv * xv, acc2);
  }

  // ---- block reduction + global atomics (only PB=200 chains/address) ----
#pragma unroll
  for (int off = 32; off > 0; off >>= 1) acc2 += __shfl_xor(acc2, off, 64);
  __shared__ float redx[4][64];
  __shared__ float red2[4];
  __shared__ int lastsh;
  redx[wid][lane] = accx;
  if (lane == 0) red2[wid] = acc2;
  __syncthreads();
  if (tid < 64) {
    float s = redx[0][tid] + redx[1][tid] + redx[2][tid] + redx[3][tid];
    atomicAdd(&stats[1 + tid], (double)s);
  }
  if (tid == 0)
    atomicAdd(&stats[0], (double)(red2[0] + red2[1] + red2[2] + red2[3]));
  __syncthreads();
  if (tid == 0) {
    __threadfence();
    int old = atomicAdd(flag, 1);
    lastsh = (old == PB - 1) ? 1 : 0;
  }
  __syncthreads();
  if (!lastsh) return;
  __threadfence();   // acquire: all blocks' stats atomics visible
  // ------- finalize (runs once, in the last-finishing block) -------
  __shared__ float sh[4];
  if (tid < 64) {
    float s = 0.f, s2 = 0.f;
    for (int tm = 0; tm < 100; tm++) { float v = tf[tm * 64 + tid]; s += v; s2 += v * v; }
    double inv16N = 1.0 / (double)(N_NODES * 16);
    double cross = (stats[1 + tid] * inv16N) * ((double)s / 100.0);
    double B = (double)s2 / 100.0;
    double term = B - 2.0 * cross;
#pragma unroll
    for (int off = 32; off > 0; off >>= 1) term += __shfl_xor(term, off, 64);
    if (tid == 0) {
      double A = stats[0] * inv16N;
      double meanM = A + term;
      float eps = (float)(0.05 * meanM) + 1e-6f;
      float a0 = alpha0[0];
      float alpha = 1.f / (1.f + expf(-a0));
      params[P_ALPHA] = alpha;
      params[P_BETA]  = 1.f - alpha;
      params[P_IEPS2] = 1.4426950408889634f / eps;
      params[P_EPS]   = eps;
      sh[0] = alpha; sh[1] = 1.f - alpha; sh[2] = 1.4426950408889634f / eps;
    }
  }
  __syncthreads();
  if (tid < 100) {
    float alpha = sh[0], beta = sh[1], ieps2 = sh[2];
    int t = tid / 10, mm = tid % 10;
    float h = 0.f;
    for (int r = 0; r < 10; r++) { float cv = c2[t * 100 + mm * 10 + r]; h += cv * cv; }
    float hc2v = 0.1f * h;
    params[P_HC2 + tid] = hc2v;
    float s2 = 0.f;
    for (int f = 0; f < 64; f++) { float v = tf[tid * 64 + f]; s2 += v * v; }
    float rs = 0.f;
    for (int m2_ = 0; m2_ < 10; m2_++) rs += c2[t * 100 + mm * 10 + m2_];
    params[P_RSC2 + tid] = rs;
    params[P_F1 + tid] = (beta * s2 + 2.0f * alpha * hc2v) * (-ieps2);
  }
}

// --------- kernel 3: single-pair fused M + drift-folded Sinkhorn ------------
// lane = (node_s, t, k). x pre-converted to f16 (2.56 MB -> L2-resident per
// XCD); whole 128B row loaded in ONE round trip (8x uint4). sink5 fully
// unrolled so iter i's tail rcps overlap iter i+1's kv FMAs.
__global__ void __launch_bounds__(320, 6)
k_main(const half_t* __restrict__ xh, const float* __restrict__ tf_g,
       const float* __restrict__ c2_g, const int* __restrict__ nbc_g,
       const int* __restrict__ neigh_g, const float* __restrict__ params,
       const float* __restrict__ s2x_g, float* __restrict__ out) {
  __shared__ __align__(16) half_t tf_l[10 * TF_STRIDE];   // 12.96 KB
  __shared__ __align__(16) float c2_l[1000];              // 4 KB
  __shared__ __align__(16) float hc2_l[100];
  __shared__ __align__(16) float rsc2_l[100];
  __shared__ __align__(16) float F1_l[100];
  __shared__ __align__(16) float bsb_l[20][10][2];

  const int tid = threadIdx.x;
  const int node_s = tid / 160;
  const int s = tid % 160;
  const int t = s >> 4;
  const int k = s & 15;
  const bool k0 = (k == 0);
  const int grp = node_s * 10 + t;

  for (int i = tid; i < 6400; i += 320) {
    int tt = i / 640, rem = i - tt * 640;
    tf_l[tt * TF_STRIDE + rem] = (half_t)tf_g[i];
  }
  for (int i = tid; i < 1000; i += 320) c2_l[i] = c2_g[i];
  if (tid < 100) {
    hc2_l[tid]  = params[P_HC2 + tid];
    rsc2_l[tid] = params[P_RSC2 + tid];
    F1_l[tid]   = params[P_F1 + tid];
  }

  // wave-uniform constants -> SGPRs
  const float alpha = sgpr(params[P_ALPHA]);
  const float beta  = sgpr(params[P_BETA]);
  const float ieps2 = sgpr(params[P_IEPS2]);
  const float eps   = sgpr(params[P_EPS]);
  const float niep  = -ieps2;
  const float twoal = 2.0f * alpha;
  const float ctv10 = 0.2f * twoal * ieps2;    // = ctv*0.1 (drift-compensated)
  const float cab   = 2.0f * beta * ieps2;
  const float c_a2d = -eps * 0.69314718056f;   // Ab -> (beta*M + 2a*cc)
  const float twoal01 = 0.1f * twoal;

  const int idx_c2 = t * 100 + ((k < 10) ? k : 9) * 10;   // C2[t][kc][*] base
  __syncthreads();

  const int kk = (k == 0) ? 0 : (k - 1);
  const half_t* tfb = &tf_l[t * TF_STRIDE];
  // prefetch pointer-chase chain for first pair
  int p = blockIdx.x;
  int nb_pf = nbc_g[2 * p + node_s];
  int nbr_pf = neigh_g[(2 * p + node_s) * KN + kk];

#pragma unroll 1
  for (; p < NPAIRS; p += gridDim.x) {
    const int v = 2 * p + node_s;
    const int nb = nb_pf;
    const int srcn = (k == 0) ? v : (kk < nb ? nbr_pf : 0);
    const float s2x = s2x_g[srcn];
    const uint4* xr = (const uint4*)(xh + (size_t)srcn * 64);

    // ---- issue the whole 128B row: 8 independent uint4 loads ----
    uint4 q[8];
#pragma unroll
    for (int r = 0; r < 8; r++) q[r] = xr[r];

    // prefetch next pair's chain (clamped; unused on last iteration)
    {
      int vn = 2 * (p + gridDim.x) + node_s;
      vn = vn < N_NODES ? vn : 0;
      nb_pf = nbc_g[vn];
      nbr_pf = neigh_g[vn * KN + kk];
    }

    // ---- per-lane M dot products: f16 row regs x LDS templates ----
    float acc[10];
#pragma unroll
    for (int m = 0; m < 10; m++) {
      float a = 0.0f;
#pragma unroll
      for (int ch = 0; ch < 4; ch++) {        // same per-acc order as before
        uint4 tqa = *(const uint4*)&tfb[m * 64 + ch * 16];
        uint4 tqb = *(const uint4*)&tfb[m * 64 + ch * 16 + 8];
        const uint4 qa = q[2 * ch];
        const uint4 qb = q[2 * ch + 1];
        a = fdot2(h2(tqa.x), h2(qa.x), a);
        a = fdot2(h2(tqa.y), h2(qa.y), a);
        a = fdot2(h2(tqa.z), h2(qa.z), a);
        a = fdot2(h2(tqa.w), h2(qa.w), a);
        a = fdot2(h2(tqb.x), h2(qb.x), a);
        a = fdot2(h2(tqb.y), h2(qb.y), a);
        a = fdot2(h2(tqb.z), h2(qb.z), a);
        a = fdot2(h2(tqb.w), h2(qb.w), a);
      }
      acc[m] = a;
    }

    // ---- per-pair scalars ----
    const float inv = 1.0f / (float)(1 + nb);
    const float pk = (k <= nb) ? inv : 0.0f;
    const float hC1k = (k == 0) ? (float)nb * inv : ((k <= nb) ? inv : 0.0f);
    const float base = (beta * s2x + twoal * hC1k) * niep;
    const float ctm  = ctv10 * ((k == 0) ? (float)nb * inv : inv);

    float Ab[10];
#pragma unroll
    for (int j = 0; j < 5; j++) {
      float2 f1v = *(const float2*)&F1_l[t * 10 + 2 * j];
      Ab[2 * j]     = fmaf(cab, acc[2 * j],     f1v.x + base);
      Ab[2 * j + 1] = fmaf(cab, acc[2 * j + 1], f1v.y + base);
    }

    float K[10], vv[10];
    float u = 1.0f;
#pragma unroll
    for (int m = 0; m < 10; m++) vv[m] = 1.0f;

    // ---- outer 0: Tp = p (x) q -> tv from rowsum(C2) ----
#pragma unroll
    for (int j = 0; j < 5; j++) {
      float2 rs = *(const float2*)&rsc2_l[t * 10 + 2 * j];
      K[2 * j]     = __builtin_amdgcn_exp2f(fmaf(ctm, rs.x, Ab[2 * j]));
      K[2 * j + 1] = __builtin_amdgcn_exp2f(fmaf(ctm, rs.y, Ab[2 * j + 1]));
    }

#pragma unroll 1
    for (int o = 0; o < 3; o++) {
      // 5 drift-folded Sinkhorn iterations, fully unrolled for cross-iter ILP
#pragma unroll
      for (int it = 0; it < 5; it++) {
        float kv0 = 0.0f, kv1 = 0.0f;
#pragma unroll
        for (int m = 0; m < 10; m += 2) {
          kv0 = fmaf(K[m],     vv[m],     kv0);
          kv1 = fmaf(K[m + 1], vv[m + 1], kv1);
        }
        u = pk * __builtin_amdgcn_rcpf(kv0 + kv1);
#pragma unroll
        for (int m = 0; m < 10; m++) {
          float w = sum16(K[m] * u);
          vv[m] = __builtin_amdgcn_rcpf(w);
        }
      }
      if (o == 2) break;
      // ---- site: recompute K from current Tp (tk' = 10*Tp) ----
      {
        float B = 0.0f, SB = 0.0f;
#pragma unroll
        for (int j = 0; j < 5; j++) {
          float2 c2p = *(const float2*)&c2_l[idx_c2 + 2 * j];
          float tka = K[2 * j] * vv[2 * j] * u;
          float tkb = K[2 * j + 1] * vv[2 * j + 1] * u;
          B  = fmaf(bcast16(tka), c2p.x, B);
          SB = fmaf(sum16(tka),   c2p.x, SB);
          B  = fmaf(bcast16(tkb), c2p.y, B);
          SB = fmaf(sum16(tkb),   c2p.y, SB);
        }
        if (k < 10) { bsb_l[grp][k][0] = B; bsb_l[grp][k][1] = SB; }
        __threadfence_block();
#pragma unroll
        for (int j = 0; j < 5; j++) {
          float4 bv = *(const float4*)&bsb_l[grp][2 * j][0];
          float tva = k0 ? (bv.y - bv.x) : bv.x;
          float tvb = k0 ? (bv.w - bv.z) : bv.z;
          K[2 * j]     = __builtin_amdgcn_exp2f(fmaf(ctv10, tva, Ab[2 * j]));
          K[2 * j + 1] = __builtin_amdgcn_exp2f(fmaf(ctv10, tvb, Ab[2 * j + 1]));
        }
        __threadfence_block();
      }
    }

    // ---- final: distance. coeff = c_a2d*Ab - alpha*cc - twoal*0.1*tv' ----
    {
      float tk[10];
      float B = 0.0f, SB = 0.0f;
#pragma unroll
      for (int j = 0; j < 5; j++) {
        float2 c2p = *(const float2*)&c2_l[idx_c2 + 2 * j];
        tk[2 * j]     = K[2 * j] * vv[2 * j] * u;
        tk[2 * j + 1] = K[2 * j + 1] * vv[2 * j + 1] * u;
        B  = fmaf(bcast16(tk[2 * j]), c2p.x, B);
        SB = fmaf(sum16(tk[2 * j]),   c2p.x, SB);
        B  = fmaf(bcast16(tk[2 * j + 1]), c2p.y, B);
        SB = fmaf(sum16(tk[2 * j + 1]),   c2p.y, SB);
      }
      if (k < 10) { bsb_l[grp][k][0] = B; bsb_l[grp][k][1] = SB; }
      __threadfence_block();
      float dd = 0.0f;
#pragma unroll
      for (int j = 0; j < 5; j++) {
        float4 bv = *(const float4*)&bsb_l[grp][2 * j][0];
        float2 h2v = *(const float2*)&hc2_l[t * 10 + 2 * j];
        float tva = k0 ? (bv.y - bv.x) : bv.x;
        float tvb = k0 ? (bv.w - bv.z) : bv.z;
        float c1a = fmaf(alpha, hC1k + h2v.x, twoal01 * tva);
        float c1b = fmaf(alpha, hC1k + h2v.y, twoal01 * tvb);
        float coa = fmaf(c_a2d, Ab[2 * j], -c1a);
        float cob = fmaf(c_a2d, Ab[2 * j + 1], -c1b);
        dd = fmaf(coa, tk[2 * j], dd);
        dd = fmaf(cob, tk[2 * j + 1], dd);
      }
      __threadfence_block();
      dd = sum16(dd * 0.1f);
      if (k == 0) out[v * 10 + t] = dd;
    }
  }
}

extern "C" void kernel_launch(void* const* d_in, const int* in_sizes, int n_in,
                              void* d_out, int out_size, void* d_ws, size_t ws_size,
                              hipStream_t stream) {
  const float* x  = (const float*)d_in[0];
  const int*   ei = (const int*)d_in[1];
  const float* c2 = (const float*)d_in[2];
  const float* tf = (const float*)d_in[3];
  const float* a0 = (const float*)d_in[4];
  float* out = (float*)d_out;
  char* ws = (char*)d_ws;
  int*    cnt    = (int*)(ws + OFF_CNT);
  float*  s2xh   = (float*)(ws + OFF_S2X);
  double* stats  = (double*)(ws + OFF_STATS);
  int*    flag   = (int*)(ws + OFF_FLAG);
  int*    padc   = (int*)(ws + OFF_PAD);
  int*    nbc    = (int*)(ws + OFF_NBC);
  int*    neigh  = (int*)(ws + OFF_NEIGH);
  int*    buf    = (int*)(ws + OFF_BUF);
  half_t* xhalf  = (half_t*)(ws + OFF_BUF);   // overwrites buf after k_sel
  int*    wct    = (int*)(ws + OFF_WCT);
  float*  params = (float*)(ws + OFF_PARAMS);
  (void)in_sizes; (void)n_in; (void)out_size; (void)ws_size;

  hipMemsetAsync(ws, 0, MEMSET_LEN, stream);          // cnt+s2x+stats+flag+pad
  hipMemsetAsync(ws + OFF_WCT, 0, 80000, stream);     // weight counters
  k_scatter<<<N_EDGES / 256, 256, 0, stream>>>(ei, cnt, buf);
  k_sel<<<SS_BLOCKS, 256, 0, stream>>>(ei, cnt, buf, nbc, neigh, wct, padc);
  k_pass<<<PB, 256, 0, stream>>>(x, xhalf, wct, padc, s2xh, stats, flag,
                                 tf, c2, a0, params);
  k_main<<<GRID_MAIN, 320, 0, stream>>>(xhalf, tf, c2, nbc, neigh, params, s2xh, out);
}

// Round 5
// 369.559 us; speedup vs baseline: 1.1394x; 1.0333x over previous
//
#include <hip/hip_runtime.h>

#define N_NODES 20000
#define NPAIRS  10000
#define N_EDGES 320000
#define CAP     48
#define KN      15
#define GRID_MAIN 2500

typedef _Float16 half_t;
typedef _Float16 half2_t __attribute__((ext_vector_type(2)));
typedef float f32x2 __attribute__((ext_vector_type(2)));

// params float-index layout
#define P_ALPHA 0
#define P_BETA  1
#define P_IEPS2 2
#define P_EPS   3
#define P_HC2   16
#define P_RSC2  216
#define P_F1    316

// workspace byte offsets
#define OFF_CNT    0u             // 80 KB
#define OFF_S2X    80000u         // 80 KB
#define OFF_STATS  160000u        // 65 doubles (520 B)
#define OFF_FLAG   160520u        // last-block-done counter (int)
#define OFF_PAD    160524u        // global pad count (int)
#define OFF_NBC    160528u
#define OFF_NEIGH  240528u
#define OFF_BUF    1440528u       // 3.84 MB edge-slot buf; xh (2.56 MB) overwrites
#define OFF_WCT    5280528u       // 80 KB neighbor-weight counters (in old buf tail)
#define OFF_PARAMS 6560528u
#define MEMSET_LEN 160528u        // cnt + s2x(harmless) + stats + flag + pad

// tf_l per-template stride (halfs): dword stride 324 = 4 (mod 32)
#define TF_STRIDE 648

// ---- 16-lane reduction via DPP row_ror adds: pure VALU ----
template<int CTRL>
__device__ __forceinline__ float dpp_add(float v) {
  int s = __builtin_bit_cast(int, v);
  int r = __builtin_amdgcn_update_dpp(0, s, CTRL, 0xF, 0xF, true);
  return v + __builtin_bit_cast(float, r);
}
__device__ __forceinline__ float sum16(float v) {
  v = dpp_add<0x128>(v);   // row_ror:8
  v = dpp_add<0x124>(v);   // row_ror:4
  v = dpp_add<0x122>(v);   // row_ror:2
  v = dpp_add<0x121>(v);   // row_ror:1
  return v;
}
// ds_swizzle imm BitMode 0x010: new_lane = lane&0x10 -> broadcast k=0 of group
__device__ __forceinline__ float bcast16(float v) {
  return __builtin_bit_cast(float,
      __builtin_amdgcn_ds_swizzle(__builtin_bit_cast(int, v), 0x010));
}
__device__ __forceinline__ float fdot2(half2_t a, half2_t b, float c) {
  return __builtin_amdgcn_fdot2(a, b, c, false);
}
__device__ __forceinline__ half2_t h2(unsigned int u) {
  return __builtin_bit_cast(half2_t, u);
}
// force a wave-uniform float into an SGPR
__device__ __forceinline__ float sgpr(float v) {
  return __builtin_bit_cast(float,
      __builtin_amdgcn_readfirstlane(__builtin_bit_cast(int, v)));
}
// ---- packed fp32 VALU ops: 2 independent IEEE fma/mul per instruction ----
__device__ __forceinline__ f32x2 pk_fma(f32x2 a, f32x2 b, f32x2 c) {
  f32x2 d;
  asm("v_pk_fma_f32 %0, %1, %2, %3" : "=v"(d) : "v"(a), "v"(b), "v"(c));
  return d;
}
__device__ __forceinline__ f32x2 pk_mul(f32x2 a, f32x2 b) {
  f32x2 d;
  asm("v_pk_mul_f32 %0, %1, %2" : "=v"(d) : "v"(a), "v"(b));
  return d;
}

// ---------------- kernel 1: scatter edge ids per source node ----------------
__global__ void k_scatter(const int* __restrict__ ei, int* __restrict__ cnt,
                          int* __restrict__ buf) {
  int e = blockIdx.x * blockDim.x + threadIdx.x;
  if (e >= N_EDGES) return;
  int s = ei[e];
  int slot = atomicAdd(&cnt[s], 1);
  if (slot < CAP) buf[s * CAP + slot] = e;
}

// ---- kernel 2: select 15 smallest edge ids, scatter neighbor weights ------
#define SS_BLOCKS 1250
__global__ void __launch_bounds__(256)
k_sel(const int* __restrict__ ei, const int* __restrict__ cnt,
      const int* __restrict__ buf, int* __restrict__ nbc_g,
      int* __restrict__ neigh, int* __restrict__ wct,
      int* __restrict__ padc) {
  const int lane = threadIdx.x & 63;
  const int wid = threadIdx.x >> 6;
  const int* dst = ei + N_EDGES;
  __shared__ int padsh;
  if (threadIdx.x == 0) padsh = 0;
  __syncthreads();
  int padacc = 0;

  for (int w = blockIdx.x * 4 + wid; w < N_NODES; w += SS_BLOCKS * 4) {
    int c = cnt[w];
    int cc = c < CAP ? c : CAP;
    int e = (lane < cc) ? buf[w * CAP + lane] : 0x7fffffff;
    int nb = c < KN ? c : KN;
    bool sel;
    if (cc <= KN) {
      sel = lane < cc;
    } else {
      int rank = 0;
      for (int j = 0; j < cc; j++) {      // cc is wave-uniform
        int ej = __shfl(e, j);
        rank += (ej < e) ? 1 : 0;
      }
      sel = (e != 0x7fffffff) && (rank < KN);  // distinct ids -> exactly 15
    }
    unsigned long long mask = __ballot(sel);
    if (sel) {
      int pos = __popcll(mask & ((1ull << lane) - 1ull));
      int d = dst[e];
      neigh[w * KN + pos] = d;
      atomicAdd(&wct[d], 1);             // neighbor-occurrence weight
    }
    if (lane == 0) { nbc_g[w] = nb; padacc += KN - nb; }
  }
  if (lane == 0 && padacc) atomicAdd(&padsh, padacc);
  __syncthreads();
  if (threadIdx.x == 0 && padsh) atomicAdd(padc, padsh);
}

// ---- kernel 2.5: ONE coalesced pass over x ---------------------------------
// Produces xh (f16 RTNE), s2xh, weighted eps-stats, then finalizes params.
#define PB 200
__global__ void __launch_bounds__(256)
k_pass(const float* __restrict__ x, half_t* __restrict__ xh,
       const int* __restrict__ wct, const int* __restrict__ padc,
       float* __restrict__ s2xh, double* __restrict__ stats,
       int* __restrict__ flag, const float* __restrict__ tf,
       const float* __restrict__ c2, const float* __restrict__ alpha0,
       float* __restrict__ params) {
  const int lane = threadIdx.x & 63;
  const int wid = threadIdx.x >> 6;
  const int tid = threadIdx.x;
  const int pad = *padc;
  float accx = 0.f, acc2 = 0.f;

  for (int n = blockIdx.x * 4 + wid; n < N_NODES; n += PB * 4) {
    float xv = x[n * 64 + lane];
    half_t hv = (half_t)xv;              // RTNE, matches k_main path
    xh[n * 64 + lane] = hv;
    float hf = (float)hv;
    float sq = hf * hf;
#pragma unroll
    for (int off = 32; off > 0; off >>= 1) sq += __shfl_xor(sq, off, 64);
    if (lane == 0) s2xh[n] = sq;
    float wt = (float)(1 + wct[n] + ((n == 0) ? pad : 0));
    accx = fmaf(wt, xv, accx);
    acc2 = fmaf(wt, xv * xv, acc2);
  }

  // ---- block reduction + global atomics (only PB=200 chains/address) ----
#pragma unroll
  for (int off = 32; off > 0; off >>= 1) acc2 += __shfl_xor(acc2, off, 64);
  __shared__ float redx[4][64];
  __shared__ float red2[4];
  __shared__ int lastsh;
  redx[wid][lane] = accx;
  if (lane == 0) red2[wid] = acc2;
  __syncthreads();
  if (tid < 64) {
    float s = redx[0][tid] + redx[1][tid] + redx[2][tid] + redx[3][tid];
    atomicAdd(&stats[1 + tid], (double)s);
  }
  if (tid == 0)
    atomicAdd(&stats[0], (double)(red2[0] + red2[1] + red2[2] + red2[3]));
  __syncthreads();
  if (tid == 0) {
    __threadfence();
    int old = atomicAdd(flag, 1);
    lastsh = (old == PB - 1) ? 1 : 0;
  }
  __syncthreads();
  if (!lastsh) return;
  __threadfence();   // acquire: all blocks' stats atomics visible
  // ------- finalize (runs once, in the last-finishing block) -------
  __shared__ float sh[4];
  if (tid < 64) {
    float s = 0.f, s2 = 0.f;
    for (int tm = 0; tm < 100; tm++) { float v = tf[tm * 64 + tid]; s += v; s2 += v * v; }
    double inv16N = 1.0 / (double)(N_NODES * 16);
    double cross = (stats[1 + tid] * inv16N) * ((double)s / 100.0);
    double B = (double)s2 / 100.0;
    double term = B - 2.0 * cross;
#pragma unroll
    for (int off = 32; off > 0; off >>= 1) term += __shfl_xor(term, off, 64);
    if (tid == 0) {
      double A = stats[0] * inv16N;
      double meanM = A + term;
      float eps = (float)(0.05 * meanM) + 1e-6f;
      float a0 = alpha0[0];
      float alpha = 1.f / (1.f + expf(-a0));
      params[P_ALPHA] = alpha;
      params[P_BETA]  = 1.f - alpha;
      params[P_IEPS2] = 1.4426950408889634f / eps;
      params[P_EPS]   = eps;
      sh[0] = alpha; sh[1] = 1.f - alpha; sh[2] = 1.4426950408889634f / eps;
    }
  }
  __syncthreads();
  if (tid < 100) {
    float alpha = sh[0], beta = sh[1], ieps2 = sh[2];
    int t = tid / 10, mm = tid % 10;
    float h = 0.f;
    for (int r = 0; r < 10; r++) { float cv = c2[t * 100 + mm * 10 + r]; h += cv * cv; }
    float hc2v = 0.1f * h;
    params[P_HC2 + tid] = hc2v;
    float s2 = 0.f;
    for (int f = 0; f < 64; f++) { float v = tf[tid * 64 + f]; s2 += v * v; }
    float rs = 0.f;
    for (int m2_ = 0; m2_ < 10; m2_++) rs += c2[t * 100 + mm * 10 + m2_];
    params[P_RSC2 + tid] = rs;
    params[P_F1 + tid] = (beta * s2 + 2.0f * alpha * hc2v) * (-ieps2);
  }
}

// --------- kernel 3: single-pair fused M + drift-folded Sinkhorn ------------
// lane = (node_s, t, k). m-dimension pairs packed into v_pk_fma_f32 /
// v_pk_mul_f32 (bit-identical two-lane IEEE ops); sum16 DPP chains and rcp
// stay scalar. sink5 kept as a CFG loop (unroll 1: measured faster).
__global__ void __launch_bounds__(320, 6)
k_main(const half_t* __restrict__ xh, const float* __restrict__ tf_g,
       const float* __restrict__ c2_g, const int* __restrict__ nbc_g,
       const int* __restrict__ neigh_g, const float* __restrict__ params,
       const float* __restrict__ s2x_g, float* __restrict__ out) {
  __shared__ __align__(16) half_t tf_l[10 * TF_STRIDE];   // 12.96 KB
  __shared__ __align__(16) float c2_l[1000];              // 4 KB
  __shared__ __align__(16) float hc2_l[100];
  __shared__ __align__(16) float rsc2_l[100];
  __shared__ __align__(16) float F1_l[100];
  __shared__ __align__(16) float bsb_l[20][10][2];

  const int tid = threadIdx.x;
  const int node_s = tid / 160;
  const int s = tid % 160;
  const int t = s >> 4;
  const int k = s & 15;
  const bool k0 = (k == 0);
  const int grp = node_s * 10 + t;

  for (int i = tid; i < 6400; i += 320) {
    int tt = i / 640, rem = i - tt * 640;
    tf_l[tt * TF_STRIDE + rem] = (half_t)tf_g[i];
  }
  for (int i = tid; i < 1000; i += 320) c2_l[i] = c2_g[i];
  if (tid < 100) {
    hc2_l[tid]  = params[P_HC2 + tid];
    rsc2_l[tid] = params[P_RSC2 + tid];
    F1_l[tid]   = params[P_F1 + tid];
  }

  // wave-uniform constants -> SGPRs
  const float alpha = sgpr(params[P_ALPHA]);
  const float beta  = sgpr(params[P_BETA]);
  const float ieps2 = sgpr(params[P_IEPS2]);
  const float eps   = sgpr(params[P_EPS]);
  const float niep  = -ieps2;
  const float twoal = 2.0f * alpha;
  const float ctv10 = 0.2f * twoal * ieps2;    // = ctv*0.1 (drift-compensated)
  const float cab   = 2.0f * beta * ieps2;
  const float c_a2d = -eps * 0.69314718056f;   // Ab -> (beta*M + 2a*cc)
  const float twoal01 = 0.1f * twoal;
  const f32x2 cab2 = {cab, cab};
  const f32x2 ctv2 = {ctv10, ctv10};

  const int idx_c2 = t * 100 + ((k < 10) ? k : 9) * 10;   // C2[t][kc][*] base
  __syncthreads();

  const int kk = (k == 0) ? 0 : (k - 1);
  const half_t* tfb = &tf_l[t * TF_STRIDE];
  // prefetch pointer-chase chain for first pair
  int p = blockIdx.x;
  int nb_pf = nbc_g[2 * p + node_s];
  int nbr_pf = neigh_g[(2 * p + node_s) * KN + kk];

#pragma unroll 1
  for (; p < NPAIRS; p += gridDim.x) {
    const int v = 2 * p + node_s;
    const int nb = nb_pf;
    const int srcn = (k == 0) ? v : (kk < nb ? nbr_pf : 0);
    const float s2x = s2x_g[srcn];
    const uint4* xr = (const uint4*)(xh + (size_t)srcn * 64);

    // ---- issue the whole 128B row: 8 independent uint4 loads ----
    uint4 q[8];
#pragma unroll
    for (int r = 0; r < 8; r++) q[r] = xr[r];

    // prefetch next pair's chain (clamped; unused on last iteration)
    {
      int vn = 2 * (p + gridDim.x) + node_s;
      vn = vn < N_NODES ? vn : 0;
      nb_pf = nbc_g[vn];
      nbr_pf = neigh_g[vn * KN + kk];
    }

    // ---- per-lane M dot products: f16 row regs x LDS templates ----
    float acc[10];
#pragma unroll
    for (int m = 0; m < 10; m++) {
      float a = 0.0f;
#pragma unroll
      for (int ch = 0; ch < 4; ch++) {        // same per-acc order as before
        uint4 tqa = *(const uint4*)&tfb[m * 64 + ch * 16];
        uint4 tqb = *(const uint4*)&tfb[m * 64 + ch * 16 + 8];
        const uint4 qa = q[2 * ch];
        const uint4 qb = q[2 * ch + 1];
        a = fdot2(h2(tqa.x), h2(qa.x), a);
        a = fdot2(h2(tqa.y), h2(qa.y), a);
        a = fdot2(h2(tqa.z), h2(qa.z), a);
        a = fdot2(h2(tqa.w), h2(qa.w), a);
        a = fdot2(h2(tqb.x), h2(qb.x), a);
        a = fdot2(h2(tqb.y), h2(qb.y), a);
        a = fdot2(h2(tqb.z), h2(qb.z), a);
        a = fdot2(h2(tqb.w), h2(qb.w), a);
      }
      acc[m] = a;
    }

    // ---- per-pair scalars ----
    const float inv = 1.0f / (float)(1 + nb);
    const float pk = (k <= nb) ? inv : 0.0f;
    const float hC1k = (k == 0) ? (float)nb * inv : ((k <= nb) ? inv : 0.0f);
    const float base = (beta * s2x + twoal * hC1k) * niep;
    const float ctm  = ctv10 * ((k == 0) ? (float)nb * inv : inv);
    const f32x2 base2 = {base, base};
    const f32x2 ctm2 = {ctm, ctm};

    f32x2 Ab2[5];
#pragma unroll
    for (int j = 0; j < 5; j++) {
      f32x2 f1v = *(const f32x2*)&F1_l[t * 10 + 2 * j];
      f32x2 av = {acc[2 * j], acc[2 * j + 1]};
      Ab2[j] = pk_fma(cab2, av, f1v + base2);
    }

    f32x2 K2[5], vv2[5];
    float u = 1.0f;
#pragma unroll
    for (int j = 0; j < 5; j++) { vv2[j][0] = 1.0f; vv2[j][1] = 1.0f; }

    // ---- outer 0: Tp = p (x) q -> tv from rowsum(C2) ----
#pragma unroll
    for (int j = 0; j < 5; j++) {
      f32x2 rs = *(const f32x2*)&rsc2_l[t * 10 + 2 * j];
      f32x2 arg = pk_fma(ctm2, rs, Ab2[j]);
      f32x2 Kv;
      Kv[0] = __builtin_amdgcn_exp2f(arg[0]);
      Kv[1] = __builtin_amdgcn_exp2f(arg[1]);
      K2[j] = Kv;
    }

#pragma unroll 1
    for (int o = 0; o < 3; o++) {
      // 5 drift-folded Sinkhorn iterations (m-pairs packed into pk ops)
#pragma unroll 1
      for (int it = 0; it < 5; it++) {
        f32x2 kv = {0.0f, 0.0f};
#pragma unroll
        for (int j = 0; j < 5; j++) kv = pk_fma(K2[j], vv2[j], kv);
        u = pk * __builtin_amdgcn_rcpf(kv[0] + kv[1]);
        f32x2 up = {u, u};
#pragma unroll
        for (int j = 0; j < 5; j++) {
          f32x2 Ku = pk_mul(K2[j], up);
          f32x2 nv;
          nv[0] = __builtin_amdgcn_rcpf(sum16(Ku[0]));
          nv[1] = __builtin_amdgcn_rcpf(sum16(Ku[1]));
          vv2[j] = nv;
        }
      }
      if (o == 2) break;
      // ---- site: recompute K from current Tp (tk' = 10*Tp) ----
      {
        const f32x2 up = {u, u};
        float B = 0.0f, SB = 0.0f;
#pragma unroll
        for (int j = 0; j < 5; j++) {
          float2 c2p = *(const float2*)&c2_l[idx_c2 + 2 * j];
          f32x2 tk2 = pk_mul(pk_mul(K2[j], vv2[j]), up);
          B  = fmaf(bcast16(tk2[0]), c2p.x, B);
          SB = fmaf(sum16(tk2[0]),   c2p.x, SB);
          B  = fmaf(bcast16(tk2[1]), c2p.y, B);
          SB = fmaf(sum16(tk2[1]),   c2p.y, SB);
        }
        if (k < 10) { bsb_l[grp][k][0] = B; bsb_l[grp][k][1] = SB; }
        __threadfence_block();
#pragma unroll
        for (int j = 0; j < 5; j++) {
          float4 bv = *(const float4*)&bsb_l[grp][2 * j][0];
          f32x2 tv2;
          tv2[0] = k0 ? (bv.y - bv.x) : bv.x;
          tv2[1] = k0 ? (bv.w - bv.z) : bv.z;
          f32x2 arg = pk_fma(ctv2, tv2, Ab2[j]);
          f32x2 Kv;
          Kv[0] = __builtin_amdgcn_exp2f(arg[0]);
          Kv[1] = __builtin_amdgcn_exp2f(arg[1]);
          K2[j] = Kv;
        }
        __threadfence_block();
      }
    }

    // ---- final: distance. coeff = c_a2d*Ab - alpha*cc - twoal*0.1*tv' ----
    {
      const f32x2 up = {u, u};
      f32x2 tkf[5];
      float B = 0.0f, SB = 0.0f;
#pragma unroll
      for (int j = 0; j < 5; j++) {
        float2 c2p = *(const float2*)&c2_l[idx_c2 + 2 * j];
        tkf[j] = pk_mul(pk_mul(K2[j], vv2[j]), up);
        B  = fmaf(bcast16(tkf[j][0]), c2p.x, B);
        SB = fmaf(sum16(tkf[j][0]),   c2p.x, SB);
        B  = fmaf(bcast16(tkf[j][1]), c2p.y, B);
        SB = fmaf(sum16(tkf[j][1]),   c2p.y, SB);
      }
      if (k < 10) { bsb_l[grp][k][0] = B; bsb_l[grp][k][1] = SB; }
      __threadfence_block();
      float dd = 0.0f;
#pragma unroll
      for (int j = 0; j < 5; j++) {
        float4 bv = *(const float4*)&bsb_l[grp][2 * j][0];
        float2 h2v = *(const float2*)&hc2_l[t * 10 + 2 * j];
        float tva = k0 ? (bv.y - bv.x) : bv.x;
        float tvb = k0 ? (bv.w - bv.z) : bv.z;
        float c1a = fmaf(alpha, hC1k + h2v.x, twoal01 * tva);
        float c1b = fmaf(alpha, hC1k + h2v.y, twoal01 * tvb);
        float coa = fmaf(c_a2d, Ab2[j][0], -c1a);
        float cob = fmaf(c_a2d, Ab2[j][1], -c1b);
        dd = fmaf(coa, tkf[j][0], dd);
        dd = fmaf(cob, tkf[j][1], dd);
      }
      __threadfence_block();
      dd = sum16(dd * 0.1f);
      if (k == 0) out[v * 10 + t] = dd;
    }
  }
}

extern "C" void kernel_launch(void* const* d_in, const int* in_sizes, int n_in,
                              void* d_out, int out_size, void* d_ws, size_t ws_size,
                              hipStream_t stream) {
  const float* x  = (const float*)d_in[0];
  const int*   ei = (const int*)d_in[1];
  const float* c2 = (const float*)d_in[2];
  const float* tf = (const float*)d_in[3];
  const float* a0 = (const float*)d_in[4];
  float* out = (float*)d_out;
  char* ws = (char*)d_ws;
  int*    cnt    = (int*)(ws + OFF_CNT);
  float*  s2xh   = (float*)(ws + OFF_S2X);
  double* stats  = (double*)(ws + OFF_STATS);
  int*    flag   = (int*)(ws + OFF_FLAG);
  int*    padc   = (int*)(ws + OFF_PAD);
  int*    nbc    = (int*)(ws + OFF_NBC);
  int*    neigh  = (int*)(ws + OFF_NEIGH);
  int*    buf    = (int*)(ws + OFF_BUF);
  half_t* xhalf  = (half_t*)(ws + OFF_BUF);   // overwrites buf after k_sel
  int*    wct    = (int*)(ws + OFF_WCT);
  float*  params = (float*)(ws + OFF_PARAMS);
  (void)in_sizes; (void)n_in; (void)out_size; (void)ws_size;

  hipMemsetAsync(ws, 0, MEMSET_LEN, stream);          // cnt+s2x+stats+flag+pad
  hipMemsetAsync(ws + OFF_WCT, 0, 80000, stream);     // weight counters
  k_scatter<<<N_EDGES / 256, 256, 0, stream>>>(ei, cnt, buf);
  k_sel<<<SS_BLOCKS, 256, 0, stream>>>(ei, cnt, buf, nbc, neigh, wct, padc);
  k_pass<<<PB, 256, 0, stream>>>(x, xhalf, wct, padc, s2xh, stats, flag,
                                 tf, c2, a0, params);
  k_main<<<GRID_MAIN, 320, 0, stream>>>(xhalf, tf, c2, nbc, neigh, params, s2xh, out);
}